// Round 9
// baseline (326.545 us; speedup 1.0000x reference)
//
#include <hip/hip_runtime.h>
#include <math.h>

#define BB 2
#define SS 2048
#define DD 1024
#define HH 16
#define HDD 64
static constexpr float EPS = 1e-6f;

typedef __bf16 bf16x8 __attribute__((ext_vector_type(8)));
typedef __bf16 bf16x4 __attribute__((ext_vector_type(4)));
typedef float f32x4 __attribute__((ext_vector_type(4)));
typedef __attribute__((address_space(1))) const unsigned int gas_u32;
typedef __attribute__((address_space(3))) unsigned int las_u32;

__device__ __forceinline__ unsigned short f2bf(float f) {
    unsigned int u = __float_as_uint(f);
    u = (u + 0x7FFFu + ((u >> 16) & 1u)) >> 16;   // round-to-nearest-even
    return (unsigned short)u;
}

__device__ __forceinline__ float b2f(unsigned short u) {
    return __uint_as_float((unsigned int)u << 16);
}

__device__ __forceinline__ uint2 pack4bf(float a, float b, float c, float d) {
    bf16x4 v;
    v[0] = (__bf16)a; v[1] = (__bf16)b; v[2] = (__bf16)c; v[3] = (__bf16)d;
    return *(uint2*)&v;
}

__device__ __forceinline__ void async_ld16(const unsigned short* g, unsigned short* l) {
    __builtin_amdgcn_global_load_lds((gas_u32*)g, (las_u32*)l, 16, 0, 0);
}

// ---------------------------------------------------------------------------
// Kernel 0: cast + transpose weights: w[K][N] fp32 -> wt[N][K] bf16
// ---------------------------------------------------------------------------
__global__ __launch_bounds__(256) void cast_transpose(const float* __restrict__ w,
                                                      unsigned short* __restrict__ wt,
                                                      int K, int N) {
    __shared__ float tile[32][36];
    const int n0 = blockIdx.x * 32;
    const int k0 = blockIdx.y * 32;
    const int t = threadIdx.x;
    const int r = t >> 3;
    const int c = (t & 7) * 4;
    *(float4*)&tile[r][c] = *(const float4*)(w + (size_t)(k0 + r) * N + n0 + c);
    __syncthreads();
    unsigned short o[4];
#pragma unroll
    for (int i = 0; i < 4; i++) o[i] = f2bf(tile[c + i][r]);
    *(uint2*)(wt + (size_t)(n0 + r) * K + k0 + c) = *(uint2*)o;
}

// ---------------------------------------------------------------------------
// Kernel 0b: RoPE tables: ctab/stab[s][i] = cos/sin(s * 10000^(-i/32))
// ---------------------------------------------------------------------------
__global__ __launch_bounds__(256) void rope_tables(float* __restrict__ ctab,
                                                   float* __restrict__ stab) {
    const int idx = blockIdx.x * 256 + threadIdx.x;   // 0..65535
    const int s = idx >> 5;
    const int i = idx & 31;
    const float ang = (float)s * exp2f(-(float)i * (13.287712379549449f / 32.f));
    ctab[idx] = cosf(ang);
    stab[idx] = sinf(ang);
}

// ---------------------------------------------------------------------------
// Kernel 1: LayerNorm rows of x [4096,1024] -> xn (bf16)
// ---------------------------------------------------------------------------
__global__ __launch_bounds__(256) void ln_kernel(const float* __restrict__ x,
                                                 const float* __restrict__ scale,
                                                 const float* __restrict__ bias,
                                                 unsigned short* __restrict__ xn) {
    __shared__ float red[4];
    const int row = blockIdx.x;
    const int t = threadIdx.x;
    const float* xr = x + (size_t)row * DD + t * 4;

    float4 v = *(const float4*)xr;
    float s = v.x + v.y + v.z + v.w;
#pragma unroll
    for (int o = 32; o; o >>= 1) s += __shfl_xor(s, o);
    if ((t & 63) == 0) red[t >> 6] = s;
    __syncthreads();
    const float mu = (red[0] + red[1] + red[2] + red[3]) * (1.f / DD);

    float4 d = {v.x - mu, v.y - mu, v.z - mu, v.w - mu};
    float sq = d.x * d.x + d.y * d.y + d.z * d.z + d.w * d.w;
#pragma unroll
    for (int o = 32; o; o >>= 1) sq += __shfl_xor(sq, o);
    __syncthreads();
    if ((t & 63) == 0) red[t >> 6] = sq;
    __syncthreads();
    const float var = (red[0] + red[1] + red[2] + red[3]) * (1.f / DD);
    const float rstd = rsqrtf(var + EPS);

    const float4 sc = *(const float4*)(scale + t * 4);
    const float4 bi = *(const float4*)(bias + t * 4);
    unsigned short o[4];
    o[0] = f2bf(d.x * rstd * sc.x + bi.x);
    o[1] = f2bf(d.y * rstd * sc.y + bi.y);
    o[2] = f2bf(d.z * rstd * sc.z + bi.z);
    o[3] = f2bf(d.w * rstd * sc.w + bi.w);
    *(uint2*)(xn + (size_t)row * DD + t * 4) = *(uint2*)o;
}

// ---------------------------------------------------------------------------
// Kernel 2a: bf16 MFMA GEMM, 128x128 tile, bf16 output (for QKV)
// ---------------------------------------------------------------------------
__global__ __launch_bounds__(256) void gemm_mfma_bt_bf16(const unsigned short* __restrict__ A,
                                                         const unsigned short* __restrict__ Bt,
                                                         const float* __restrict__ bias,
                                                         unsigned short* __restrict__ C,
                                                         int M, int N, int K) {
    __shared__ __align__(16) unsigned short As[128][32];
    __shared__ __align__(16) unsigned short Bs[128][32];

    const int bm = blockIdx.y * 128;
    const int bn = blockIdx.x * 128;
    const int t = threadIdx.x;
    const int wv = t >> 6;
    const int ln = t & 63;
    const int m16 = ln & 15;
    const int quad = ln >> 4;
    const int wm = (wv >> 1) * 64;
    const int wn = (wv & 1) * 64;

    f32x4 acc[4][4];
#pragma unroll
    for (int i = 0; i < 4; i++)
#pragma unroll
        for (int j = 0; j < 4; j++) acc[i][j] = (f32x4){0.f, 0.f, 0.f, 0.f};

    const int srow = wv * 32 + (ln >> 2);
    const int sk = (ln & 3) * 8;
    const unsigned short* aptr = A + (size_t)(bm + srow) * K + sk;
    const unsigned short* bptr = Bt + (size_t)(bn + srow) * K + sk;
    unsigned short* al0 = &As[wv * 32][0];
    unsigned short* al1 = &As[wv * 32 + 16][0];
    unsigned short* bl0 = &Bs[wv * 32][0];
    unsigned short* bl1 = &Bs[wv * 32 + 16][0];

    for (int k0 = 0; k0 < K; k0 += 32) {
        __syncthreads();
        async_ld16(aptr, al0);
        async_ld16(aptr + 16 * (size_t)K, al1);
        async_ld16(bptr, bl0);
        async_ld16(bptr + 16 * (size_t)K, bl1);
        __syncthreads();

        bf16x8 af[4], bf[4];
#pragma unroll
        for (int i = 0; i < 4; i++)
            af[i] = *(const bf16x8*)&As[wm + i * 16 + m16][quad * 8];
#pragma unroll
        for (int j = 0; j < 4; j++)
            bf[j] = *(const bf16x8*)&Bs[wn + j * 16 + m16][quad * 8];
#pragma unroll
        for (int i = 0; i < 4; i++)
#pragma unroll
            for (int j = 0; j < 4; j++)
                acc[i][j] = __builtin_amdgcn_mfma_f32_16x16x32_bf16(af[i], bf[j], acc[i][j], 0, 0, 0);

        aptr += 32;
        bptr += 32;
    }

#pragma unroll
    for (int j = 0; j < 4; j++) {
        const int n = bn + wn + j * 16 + m16;
        const float bv = bias[n];
#pragma unroll
        for (int i = 0; i < 4; i++) {
            unsigned short* cp = C + (size_t)(bm + wm + i * 16 + quad * 4) * N + n;
#pragma unroll
            for (int r = 0; r < 4; r++)
                cp[(size_t)r * N] = f2bf(acc[i][j][r] + bv);
        }
    }
}

// ---------------------------------------------------------------------------
// Kernel 2b: bf16 MFMA GEMM, 128x128 tile, fp32 output (out-proj)
// ---------------------------------------------------------------------------
__global__ __launch_bounds__(256) void gemm_mfma_bt(const unsigned short* __restrict__ A,
                                                    const unsigned short* __restrict__ Bt,
                                                    const float* __restrict__ bias,
                                                    float* __restrict__ C,
                                                    int M, int N, int K) {
    __shared__ __align__(16) unsigned short As[128][32];
    __shared__ __align__(16) unsigned short Bs[128][32];

    const int bm = blockIdx.y * 128;
    const int bn = blockIdx.x * 128;
    const int t = threadIdx.x;
    const int wv = t >> 6;
    const int ln = t & 63;
    const int m16 = ln & 15;
    const int quad = ln >> 4;
    const int wm = (wv >> 1) * 64;
    const int wn = (wv & 1) * 64;

    f32x4 acc[4][4];
#pragma unroll
    for (int i = 0; i < 4; i++)
#pragma unroll
        for (int j = 0; j < 4; j++) acc[i][j] = (f32x4){0.f, 0.f, 0.f, 0.f};

    const int srow = wv * 32 + (ln >> 2);
    const int sk = (ln & 3) * 8;
    const unsigned short* aptr = A + (size_t)(bm + srow) * K + sk;
    const unsigned short* bptr = Bt + (size_t)(bn + srow) * K + sk;
    unsigned short* al0 = &As[wv * 32][0];
    unsigned short* al1 = &As[wv * 32 + 16][0];
    unsigned short* bl0 = &Bs[wv * 32][0];
    unsigned short* bl1 = &Bs[wv * 32 + 16][0];

    for (int k0 = 0; k0 < K; k0 += 32) {
        __syncthreads();
        async_ld16(aptr, al0);
        async_ld16(aptr + 16 * (size_t)K, al1);
        async_ld16(bptr, bl0);
        async_ld16(bptr + 16 * (size_t)K, bl1);
        __syncthreads();

        bf16x8 af[4], bf[4];
#pragma unroll
        for (int i = 0; i < 4; i++)
            af[i] = *(const bf16x8*)&As[wm + i * 16 + m16][quad * 8];
#pragma unroll
        for (int j = 0; j < 4; j++)
            bf[j] = *(const bf16x8*)&Bs[wn + j * 16 + m16][quad * 8];
#pragma unroll
        for (int i = 0; i < 4; i++)
#pragma unroll
            for (int j = 0; j < 4; j++)
                acc[i][j] = __builtin_amdgcn_mfma_f32_16x16x32_bf16(af[i], bf[j], acc[i][j], 0, 0, 0);

        aptr += 32;
        bptr += 32;
    }

#pragma unroll
    for (int j = 0; j < 4; j++) {
        const int n = bn + wn + j * 16 + m16;
        const float bv = bias[n];
#pragma unroll
        for (int i = 0; i < 4; i++) {
            float* cp = C + (size_t)(bm + wm + i * 16 + quad * 4) * N + n;
#pragma unroll
            for (int r = 0; r < 4; r++)
                cp[(size_t)r * N] = acc[i][j][r] + bv;
        }
    }
}

// ---------------------------------------------------------------------------
// Kernel 3: per-head LN + RoPE (bf16 in/out); qt/kt/vt in [b,h,s,d]
// ---------------------------------------------------------------------------
__device__ __forceinline__ float wave_sum64(float x) {
#pragma unroll
    for (int o = 32; o; o >>= 1) x += __shfl_xor(x, o);
    return x;
}

__global__ __launch_bounds__(256) void head_ln_rope(const unsigned short* __restrict__ qkv,
                                                    const float* __restrict__ q_scale,
                                                    const float* __restrict__ k_scale,
                                                    const float* __restrict__ ctab,
                                                    const float* __restrict__ stab,
                                                    unsigned short* __restrict__ qt,
                                                    unsigned short* __restrict__ kt,
                                                    unsigned short* __restrict__ vt) {
    const int wave = (blockIdx.x * 256 + threadIdx.x) >> 6;
    const int lane = threadIdx.x & 63;
    const int h = wave & (HH - 1);
    const int row = wave >> 4;
    const int b = row >> 11;
    const int s = row & (SS - 1);

    const unsigned short* base = qkv + (size_t)row * (3 * DD) + h * HDD;
    const float qv = b2f(base[lane]);
    const float kv = b2f(base[DD + lane]);
    const unsigned short vv = base[2 * DD + lane];

    const float mq = wave_sum64(qv) * (1.f / 64.f);
    const float dq = qv - mq;
    const float varq = wave_sum64(dq * dq) * (1.f / 64.f);
    const float yq = dq * rsqrtf(varq + EPS) * q_scale[lane];

    const float mk = wave_sum64(kv) * (1.f / 64.f);
    const float dk = kv - mk;
    const float vark = wave_sum64(dk * dk) * (1.f / 64.f);
    const float yk = dk * rsqrtf(vark + EPS) * k_scale[lane];

    const int i = lane & 31;
    const float cv = ctab[s * 32 + i];
    const float sv = stab[s * 32 + i];
    const float pq = __shfl_xor(yq, 32);
    const float pk = __shfl_xor(yk, 32);
    const float rq = (lane < 32) ? -pq : pq;
    const float rk = (lane < 32) ? -pk : pk;
    const float oq = yq * cv + rq * sv;
    const float ok = yk * cv + rk * sv;

    const size_t oidx = (((size_t)(b * HH + h) * SS) + s) * HDD + lane;
    qt[oidx] = f2bf(oq * 0.18033688011112042f);   // 0.125 * log2(e)
    kt[oidx] = f2bf(ok);
    vt[oidx] = vv;
}

// ---------------------------------------------------------------------------
// Kernel 3b: V transpose  [bh][s][d] -> [bh][d][s]  (bf16)
// ---------------------------------------------------------------------------
__global__ __launch_bounds__(256) void transpose_v(const unsigned short* __restrict__ vt,
                                                   unsigned short* __restrict__ vtT) {
    __shared__ unsigned short tile[64][72];
    const int bh = blockIdx.x >> 5;
    const int s0 = (blockIdx.x & 31) * 64;
    const int t = threadIdx.x;
    const int row = t >> 2;
    const int c0 = (t & 3) * 16;
    const unsigned short* src = vt + ((size_t)bh * SS + s0 + row) * HDD + c0;
    *(uint4*)&tile[row][c0]     = *(const uint4*)(src);
    *(uint4*)&tile[row][c0 + 8] = *(const uint4*)(src + 8);
    __syncthreads();
    unsigned short outv[16];
#pragma unroll
    for (int i = 0; i < 16; i++) outv[i] = tile[c0 + i][row];
    unsigned short* dst = vtT + ((size_t)bh * HDD + row) * SS + s0 + c0;
    *(uint4*)dst       = *(uint4*)&outv[0];
    *(uint4*)(dst + 8) = *(uint4*)&outv[8];
}

// ---------------------------------------------------------------------------
// Kernel 4: MFMA flash attention — register K/V, software-pipelined.
// K/V fragments double-buffered in VGPRs, prefetched one tile ahead (vmcnt
// keeps them in flight across current-tile compute). No __syncthreads; LDS
// only for per-wave P (16 KB). split-K x2, fixed max M=12, exp2 domain,
// l via ones-MFMA.
// ---------------------------------------------------------------------------
__global__ __launch_bounds__(256, 2) void attn_mfma(const unsigned short* __restrict__ qt,
                                                    const unsigned short* __restrict__ kt,
                                                    const unsigned short* __restrict__ vtT,
                                                    float* __restrict__ Opart,
                                                    float* __restrict__ lpart) {
    __shared__ __align__(16) unsigned short PbS[4][32 * 64];  // 16 KB, per-wave

    const int bh = blockIdx.x >> 4;
    const int q0 = (blockIdx.x & 15) * 128;
    const int ks = blockIdx.y;
    const int t = threadIdx.x;
    const int wq = t >> 6;
    const int lane = t & 63;
    const int m16 = lane & 15;
    const int quad = lane >> 4;
    const int m7 = m16 & 7;

    const int koff = m16 * 64 + (quad ^ m7) * 8;   // swizzled P-frag read base
    const int pwb = m16 * 64 + 4 * (quad & 1);     // swizzled P-write base
    const int qh = quad >> 1;

    // Q B-fragments, fixed all kernel
    bf16x8 qb[2][2];
#pragma unroll
    for (int u = 0; u < 2; u++) {
        const unsigned short* qp =
            qt + ((size_t)bh * SS + q0 + wq * 32 + u * 16 + m16) * HDD + quad * 8;
        qb[u][0] = *(const bf16x8*)qp;
        qb[u][1] = *(const bf16x8*)(qp + 32);
    }

    bf16x8 ones;
#pragma unroll
    for (int j = 0; j < 8; j++) ones[j] = (__bf16)1.0f;

    f32x4 O[2][4];
#pragma unroll
    for (int u = 0; u < 2; u++)
#pragma unroll
        for (int f = 0; f < 4; f++) O[u][f] = (f32x4){0.f, 0.f, 0.f, 0.f};
    f32x4 lacc[2] = {(f32x4){0.f, 0.f, 0.f, 0.f}, (f32x4){0.f, 0.f, 0.f, 0.f}};

    const f32x4 cinit = (f32x4){-12.f, -12.f, -12.f, -12.f};
    const int kstart = ks * (SS / 2);

    // per-lane pointers (advanced per tile pair; frag offsets via imm-friendly adds)
    const unsigned short* kl = kt + ((size_t)bh * SS + kstart + m16) * HDD + quad * 8;
    const unsigned short* vl = vtT + ((size_t)bh * HDD + m16) * SS + kstart + quad * 8;

    bf16x8 kA[4][2], vA[4][2], kB[4][2], vB[4][2];

    auto loadK = [&](const unsigned short* p, bf16x8 (&dst)[4][2]) {
#pragma unroll
        for (int g = 0; g < 4; g++) {
            dst[g][0] = *(const bf16x8*)(p + g * 16 * HDD);
            dst[g][1] = *(const bf16x8*)(p + g * 16 * HDD + 32);
        }
    };
    auto loadV = [&](const unsigned short* p, bf16x8 (&dst)[4][2]) {
#pragma unroll
        for (int f = 0; f < 4; f++) {
            dst[f][0] = *(const bf16x8*)(p + (size_t)f * 16 * SS);
            dst[f][1] = *(const bf16x8*)(p + (size_t)f * 16 * SS + 32);
        }
    };

    auto compute = [&](bf16x8 (&ka)[4][2], bf16x8 (&va)[4][2]) {
        // S^T = K @ Q^T - 12 ; p = exp2(S); packed swizzled P store
#pragma unroll
        for (int u = 0; u < 2; u++) {
            f32x4 S[4];
#pragma unroll
            for (int g = 0; g < 4; g++) {
                S[g] = __builtin_amdgcn_mfma_f32_16x16x32_bf16(ka[g][0], qb[u][0], cinit, 0, 0, 0);
                S[g] = __builtin_amdgcn_mfma_f32_16x16x32_bf16(ka[g][1], qb[u][1], S[g], 0, 0, 0);
            }
#pragma unroll
            for (int g = 0; g < 4; g++) {
                const float p0 = exp2f(S[g][0]);
                const float p1 = exp2f(S[g][1]);
                const float p2 = exp2f(S[g][2]);
                const float p3 = exp2f(S[g][3]);
                *(uint2*)&PbS[wq][u * 1024 + pwb + ((2 * g + qh) ^ m7) * 8] =
                    pack4bf(p0, p1, p2, p3);
            }
        }
        asm volatile("s_waitcnt lgkmcnt(0)" ::: "memory");

#pragma unroll
        for (int u = 0; u < 2; u++) {
            const bf16x8 pb0 = *(const bf16x8*)&PbS[wq][u * 1024 + koff];
            const bf16x8 pb1 = *(const bf16x8*)&PbS[wq][u * 1024 + (koff ^ 32)];
            lacc[u] = __builtin_amdgcn_mfma_f32_16x16x32_bf16(ones, pb0, lacc[u], 0, 0, 0);
            lacc[u] = __builtin_amdgcn_mfma_f32_16x16x32_bf16(ones, pb1, lacc[u], 0, 0, 0);
#pragma unroll
            for (int f = 0; f < 4; f++) {
                O[u][f] = __builtin_amdgcn_mfma_f32_16x16x32_bf16(va[f][0], pb0, O[u][f], 0, 0, 0);
                O[u][f] = __builtin_amdgcn_mfma_f32_16x16x32_bf16(va[f][1], pb1, O[u][f], 0, 0, 0);
            }
        }
    };

    // software pipeline: prefetch tile 0, then unroll-2 ping-pong
    loadK(kl, kA);
    loadV(vl, vA);
    const int NT = (SS / 2) / 64;   // 16 tiles
    for (int it = 0; it < NT; it += 2) {
        loadK(kl + 64 * HDD, kB);       // prefetch tile it+1
        loadV(vl + 64, vB);
        compute(kA, vA);                // tile it
        kl += 128 * HDD;
        vl += 128;
        if (it + 2 < NT) {              // prefetch tile it+2
            loadK(kl, kA);
            loadV(vl, vA);
        }
        compute(kB, vB);                // tile it+1
    }

    // epilogue: fp32 partial O + l (combine kernel normalizes)
    const int b_ = bh >> 4;
    const int h_ = bh & 15;
    float* obase0 = Opart + (size_t)ks * ((size_t)BB * SS * DD);
#pragma unroll
    for (int u = 0; u < 2; u++) {
        const int s_ = q0 + wq * 32 + u * 16 + m16;
        float* orow = obase0 + ((size_t)b_ * SS + s_) * DD + h_ * HDD;
#pragma unroll
        for (int f = 0; f < 4; f++)
            *(f32x4*)(orow + f * 16 + quad * 4) = O[u][f];
        if (quad == 0)
            lpart[ks * (32 * SS) + bh * SS + s_] = lacc[u][0];
    }
}

// ---------------------------------------------------------------------------
// Kernel 4b: combine split-K partials -> bf16 attn [b][s][h*64+d]
// ---------------------------------------------------------------------------
__global__ __launch_bounds__(256) void combine_attn(const float* __restrict__ Opart,
                                                    const float* __restrict__ lpart,
                                                    unsigned short* __restrict__ attn) {
    const int row = blockIdx.x;            // 0..4095 = b*S+s
    const int t = threadIdx.x;
    const int c = t * 4;
    const int h = t >> 4;
    const int b = row >> 11;
    const int s = row & (SS - 1);

    const size_t off = (size_t)row * DD + c;
    const float4 o0 = *(const float4*)(Opart + off);
    const float4 o1 = *(const float4*)(Opart + (size_t)BB * SS * DD + off);
    const int li = (b * HH + h) * SS + s;
    const float inv = 1.f / (lpart[li] + lpart[32 * SS + li]);

    *(uint2*)(attn + off) = pack4bf((o0.x + o1.x) * inv, (o0.y + o1.y) * inv,
                                    (o0.z + o1.z) * inv, (o0.w + o1.w) * inv);
}

// ---------------------------------------------------------------------------
// launch
// ---------------------------------------------------------------------------
extern "C" void kernel_launch(void* const* d_in, const int* in_sizes, int n_in,
                              void* d_out, int out_size, void* d_ws, size_t ws_size,
                              hipStream_t stream) {
    const float* x        = (const float*)d_in[0];
    const float* w_qkv    = (const float*)d_in[1];
    const float* b_qkv    = (const float*)d_in[2];
    const float* w_out    = (const float*)d_in[3];
    const float* b_out    = (const float*)d_in[4];
    const float* ln_scale = (const float*)d_in[5];
    const float* ln_bias  = (const float*)d_in[6];
    const float* q_scale  = (const float*)d_in[7];
    const float* k_scale  = (const float*)d_in[8];
    float* out = (float*)d_out;

    char* ws = (char*)d_ws;
    const size_t MB = 1024 * 1024;
    // layout:
    //   [0,8)    xn (bf16)
    //   [8,8.5)  lpart   [9,9.25) ctab   [10,10.25) stab
    //   [16,40)  qkv (bf16) — consumed by head_ln_rope, then
    //   [16,48)  Opart (fp32, 2 splits) reuses it
    //   [64,70)  wqkvT  [70,72) woutT  [72,80) qt  [80,88) kt
    //   [88,96)  vt     [96,104) vtT   [104,112) attn
    unsigned short* xn    = (unsigned short*)(ws + 0);
    float*          lpart = (float*)(ws + 8 * MB);
    float*          ctab  = (float*)(ws + 9 * MB);
    float*          stab  = (float*)(ws + 10 * MB);
    unsigned short* qkv   = (unsigned short*)(ws + 16 * MB);
    float*          Opart = (float*)(ws + 16 * MB);
    unsigned short* wqkvT = (unsigned short*)(ws + 64 * MB);
    unsigned short* woutT = (unsigned short*)(ws + 70 * MB);
    unsigned short* qt    = (unsigned short*)(ws + 72 * MB);
    unsigned short* kt    = (unsigned short*)(ws + 80 * MB);
    unsigned short* vt    = (unsigned short*)(ws + 88 * MB);
    unsigned short* vtT   = (unsigned short*)(ws + 96 * MB);
    unsigned short* attn  = (unsigned short*)(ws + 104 * MB);

    const int M = BB * SS;   // 4096

    cast_transpose<<<dim3(3 * DD / 32, DD / 32), 256, 0, stream>>>(w_qkv, wqkvT, DD, 3 * DD);
    cast_transpose<<<dim3(DD / 32, DD / 32), 256, 0, stream>>>(w_out, woutT, DD, DD);
    rope_tables<<<SS * 32 / 256, 256, 0, stream>>>(ctab, stab);

    ln_kernel<<<M, 256, 0, stream>>>(x, ln_scale, ln_bias, xn);

    gemm_mfma_bt_bf16<<<dim3(3 * DD / 128, M / 128), 256, 0, stream>>>(xn, wqkvT, b_qkv,
                                                                       qkv, M, 3 * DD, DD);

    head_ln_rope<<<M * HH / 4, 256, 0, stream>>>(qkv, q_scale, k_scale, ctab, stab,
                                                 qt, kt, vt);

    transpose_v<<<BB * HH * (SS / 64), 256, 0, stream>>>(vt, vtT);

    attn_mfma<<<dim3(BB * HH * (SS / 128), 2), 256, 0, stream>>>(qt, kt, vtT, Opart, lpart);

    combine_attn<<<M, 256, 0, stream>>>(Opart, lpart, attn);

    gemm_mfma_bt<<<dim3(DD / 128, M / 128), 256, 0, stream>>>(attn, woutT, b_out, out,
                                                              M, DD, DD);
}

// Round 10
// 254.991 us; speedup vs baseline: 1.2806x; 1.2806x over previous
//
#include <hip/hip_runtime.h>
#include <math.h>

#define BB 2
#define SS 2048
#define DD 1024
#define HH 16
#define HDD 64
static constexpr float EPS = 1e-6f;

typedef __bf16 bf16x8 __attribute__((ext_vector_type(8)));
typedef __bf16 bf16x4 __attribute__((ext_vector_type(4)));
typedef float f32x4 __attribute__((ext_vector_type(4)));
typedef __attribute__((address_space(1))) const unsigned int gas_u32;
typedef __attribute__((address_space(3))) unsigned int las_u32;

__device__ __forceinline__ unsigned short f2bf(float f) {
    unsigned int u = __float_as_uint(f);
    u = (u + 0x7FFFu + ((u >> 16) & 1u)) >> 16;   // round-to-nearest-even
    return (unsigned short)u;
}

__device__ __forceinline__ float b2f(unsigned short u) {
    return __uint_as_float((unsigned int)u << 16);
}

__device__ __forceinline__ uint2 pack4bf(float a, float b, float c, float d) {
    bf16x4 v;
    v[0] = (__bf16)a; v[1] = (__bf16)b; v[2] = (__bf16)c; v[3] = (__bf16)d;
    return *(uint2*)&v;
}

__device__ __forceinline__ unsigned int pack2bf(float a, float b) {
    return (unsigned int)f2bf(a) | ((unsigned int)f2bf(b) << 16);
}

__device__ __forceinline__ void async_ld16(const unsigned short* g, unsigned short* l) {
    __builtin_amdgcn_global_load_lds((gas_u32*)g, (las_u32*)l, 16, 0, 0);
}

// ---------------------------------------------------------------------------
// Kernel 0: cast + transpose weights: w[K][N] fp32 -> wt[N][K] bf16
// ---------------------------------------------------------------------------
__global__ __launch_bounds__(256) void cast_transpose(const float* __restrict__ w,
                                                      unsigned short* __restrict__ wt,
                                                      int K, int N) {
    __shared__ float tile[32][36];
    const int n0 = blockIdx.x * 32;
    const int k0 = blockIdx.y * 32;
    const int t = threadIdx.x;
    const int r = t >> 3;
    const int c = (t & 7) * 4;
    *(float4*)&tile[r][c] = *(const float4*)(w + (size_t)(k0 + r) * N + n0 + c);
    __syncthreads();
    unsigned short o[4];
#pragma unroll
    for (int i = 0; i < 4; i++) o[i] = f2bf(tile[c + i][r]);
    *(uint2*)(wt + (size_t)(n0 + r) * K + k0 + c) = *(uint2*)o;
}

// ---------------------------------------------------------------------------
// Kernel 0b: RoPE tables: ctab/stab[s][i] = cos/sin(s * 10000^(-i/32))
// ---------------------------------------------------------------------------
__global__ __launch_bounds__(256) void rope_tables(float* __restrict__ ctab,
                                                   float* __restrict__ stab) {
    const int idx = blockIdx.x * 256 + threadIdx.x;   // 0..65535
    const int s = idx >> 5;
    const int i = idx & 31;
    const float ang = (float)s * exp2f(-(float)i * (13.287712379549449f / 32.f));
    ctab[idx] = cosf(ang);
    stab[idx] = sinf(ang);
}

// ---------------------------------------------------------------------------
// Kernel 1: LayerNorm rows of x [4096,1024] -> xn (bf16)
// ---------------------------------------------------------------------------
__global__ __launch_bounds__(256) void ln_kernel(const float* __restrict__ x,
                                                 const float* __restrict__ scale,
                                                 const float* __restrict__ bias,
                                                 unsigned short* __restrict__ xn) {
    __shared__ float red[4];
    const int row = blockIdx.x;
    const int t = threadIdx.x;
    const float* xr = x + (size_t)row * DD + t * 4;

    float4 v = *(const float4*)xr;
    float s = v.x + v.y + v.z + v.w;
#pragma unroll
    for (int o = 32; o; o >>= 1) s += __shfl_xor(s, o);
    if ((t & 63) == 0) red[t >> 6] = s;
    __syncthreads();
    const float mu = (red[0] + red[1] + red[2] + red[3]) * (1.f / DD);

    float4 d = {v.x - mu, v.y - mu, v.z - mu, v.w - mu};
    float sq = d.x * d.x + d.y * d.y + d.z * d.z + d.w * d.w;
#pragma unroll
    for (int o = 32; o; o >>= 1) sq += __shfl_xor(sq, o);
    __syncthreads();
    if ((t & 63) == 0) red[t >> 6] = sq;
    __syncthreads();
    const float var = (red[0] + red[1] + red[2] + red[3]) * (1.f / DD);
    const float rstd = rsqrtf(var + EPS);

    const float4 sc = *(const float4*)(scale + t * 4);
    const float4 bi = *(const float4*)(bias + t * 4);
    unsigned short o[4];
    o[0] = f2bf(d.x * rstd * sc.x + bi.x);
    o[1] = f2bf(d.y * rstd * sc.y + bi.y);
    o[2] = f2bf(d.z * rstd * sc.z + bi.z);
    o[3] = f2bf(d.w * rstd * sc.w + bi.w);
    *(uint2*)(xn + (size_t)row * DD + t * 4) = *(uint2*)o;
}

// ---------------------------------------------------------------------------
// Kernel 2a: bf16 MFMA GEMM, 128x128 tile, bf16 output (for QKV)
// ---------------------------------------------------------------------------
__global__ __launch_bounds__(256) void gemm_mfma_bt_bf16(const unsigned short* __restrict__ A,
                                                         const unsigned short* __restrict__ Bt,
                                                         const float* __restrict__ bias,
                                                         unsigned short* __restrict__ C,
                                                         int M, int N, int K) {
    __shared__ __align__(16) unsigned short As[128][32];
    __shared__ __align__(16) unsigned short Bs[128][32];

    const int bm = blockIdx.y * 128;
    const int bn = blockIdx.x * 128;
    const int t = threadIdx.x;
    const int wv = t >> 6;
    const int ln = t & 63;
    const int m16 = ln & 15;
    const int quad = ln >> 4;
    const int wm = (wv >> 1) * 64;
    const int wn = (wv & 1) * 64;

    f32x4 acc[4][4];
#pragma unroll
    for (int i = 0; i < 4; i++)
#pragma unroll
        for (int j = 0; j < 4; j++) acc[i][j] = (f32x4){0.f, 0.f, 0.f, 0.f};

    const int srow = wv * 32 + (ln >> 2);
    const int sk = (ln & 3) * 8;
    const unsigned short* aptr = A + (size_t)(bm + srow) * K + sk;
    const unsigned short* bptr = Bt + (size_t)(bn + srow) * K + sk;
    unsigned short* al0 = &As[wv * 32][0];
    unsigned short* al1 = &As[wv * 32 + 16][0];
    unsigned short* bl0 = &Bs[wv * 32][0];
    unsigned short* bl1 = &Bs[wv * 32 + 16][0];

    for (int k0 = 0; k0 < K; k0 += 32) {
        __syncthreads();
        async_ld16(aptr, al0);
        async_ld16(aptr + 16 * (size_t)K, al1);
        async_ld16(bptr, bl0);
        async_ld16(bptr + 16 * (size_t)K, bl1);
        __syncthreads();

        bf16x8 af[4], bf[4];
#pragma unroll
        for (int i = 0; i < 4; i++)
            af[i] = *(const bf16x8*)&As[wm + i * 16 + m16][quad * 8];
#pragma unroll
        for (int j = 0; j < 4; j++)
            bf[j] = *(const bf16x8*)&Bs[wn + j * 16 + m16][quad * 8];
#pragma unroll
        for (int i = 0; i < 4; i++)
#pragma unroll
            for (int j = 0; j < 4; j++)
                acc[i][j] = __builtin_amdgcn_mfma_f32_16x16x32_bf16(af[i], bf[j], acc[i][j], 0, 0, 0);

        aptr += 32;
        bptr += 32;
    }

#pragma unroll
    for (int j = 0; j < 4; j++) {
        const int n = bn + wn + j * 16 + m16;
        const float bv = bias[n];
#pragma unroll
        for (int i = 0; i < 4; i++) {
            unsigned short* cp = C + (size_t)(bm + wm + i * 16 + quad * 4) * N + n;
#pragma unroll
            for (int r = 0; r < 4; r++)
                cp[(size_t)r * N] = f2bf(acc[i][j][r] + bv);
        }
    }
}

// ---------------------------------------------------------------------------
// Kernel 2b: bf16 MFMA GEMM, 128x128 tile, fp32 output (out-proj)
// ---------------------------------------------------------------------------
__global__ __launch_bounds__(256) void gemm_mfma_bt(const unsigned short* __restrict__ A,
                                                    const unsigned short* __restrict__ Bt,
                                                    const float* __restrict__ bias,
                                                    float* __restrict__ C,
                                                    int M, int N, int K) {
    __shared__ __align__(16) unsigned short As[128][32];
    __shared__ __align__(16) unsigned short Bs[128][32];

    const int bm = blockIdx.y * 128;
    const int bn = blockIdx.x * 128;
    const int t = threadIdx.x;
    const int wv = t >> 6;
    const int ln = t & 63;
    const int m16 = ln & 15;
    const int quad = ln >> 4;
    const int wm = (wv >> 1) * 64;
    const int wn = (wv & 1) * 64;

    f32x4 acc[4][4];
#pragma unroll
    for (int i = 0; i < 4; i++)
#pragma unroll
        for (int j = 0; j < 4; j++) acc[i][j] = (f32x4){0.f, 0.f, 0.f, 0.f};

    const int srow = wv * 32 + (ln >> 2);
    const int sk = (ln & 3) * 8;
    const unsigned short* aptr = A + (size_t)(bm + srow) * K + sk;
    const unsigned short* bptr = Bt + (size_t)(bn + srow) * K + sk;
    unsigned short* al0 = &As[wv * 32][0];
    unsigned short* al1 = &As[wv * 32 + 16][0];
    unsigned short* bl0 = &Bs[wv * 32][0];
    unsigned short* bl1 = &Bs[wv * 32 + 16][0];

    for (int k0 = 0; k0 < K; k0 += 32) {
        __syncthreads();
        async_ld16(aptr, al0);
        async_ld16(aptr + 16 * (size_t)K, al1);
        async_ld16(bptr, bl0);
        async_ld16(bptr + 16 * (size_t)K, bl1);
        __syncthreads();

        bf16x8 af[4], bf[4];
#pragma unroll
        for (int i = 0; i < 4; i++)
            af[i] = *(const bf16x8*)&As[wm + i * 16 + m16][quad * 8];
#pragma unroll
        for (int j = 0; j < 4; j++)
            bf[j] = *(const bf16x8*)&Bs[wn + j * 16 + m16][quad * 8];
#pragma unroll
        for (int i = 0; i < 4; i++)
#pragma unroll
            for (int j = 0; j < 4; j++)
                acc[i][j] = __builtin_amdgcn_mfma_f32_16x16x32_bf16(af[i], bf[j], acc[i][j], 0, 0, 0);

        aptr += 32;
        bptr += 32;
    }

#pragma unroll
    for (int j = 0; j < 4; j++) {
        const int n = bn + wn + j * 16 + m16;
        const float bv = bias[n];
#pragma unroll
        for (int i = 0; i < 4; i++) {
            float* cp = C + (size_t)(bm + wm + i * 16 + quad * 4) * N + n;
#pragma unroll
            for (int r = 0; r < 4; r++)
                cp[(size_t)r * N] = acc[i][j][r] + bv;
        }
    }
}

// ---------------------------------------------------------------------------
// Kernel 3: per-head LN + RoPE, 2 elems/lane (wave = head PAIR).
// lanes 0-31: head 2*hp, lanes 32-63: head 2*hp+1; lane li handles d=2li,2li+1.
// Half-wave reductions (5 xor steps); RoPE pair via shfl_xor(.,16).
// ---------------------------------------------------------------------------
__device__ __forceinline__ float half_sum32(float x) {
#pragma unroll
    for (int o = 16; o; o >>= 1) x += __shfl_xor(x, o);
    return x;
}

__global__ __launch_bounds__(256) void head_ln_rope(const unsigned short* __restrict__ qkv,
                                                    const float* __restrict__ q_scale,
                                                    const float* __restrict__ k_scale,
                                                    const float* __restrict__ ctab,
                                                    const float* __restrict__ stab,
                                                    unsigned short* __restrict__ qt,
                                                    unsigned short* __restrict__ kt,
                                                    unsigned short* __restrict__ vt) {
    const int wave = (blockIdx.x * 256 + threadIdx.x) >> 6;  // 0..32767
    const int lane = threadIdx.x & 63;
    const int hp = wave & 7;                 // head pair
    const int row = wave >> 3;               // 0..4095
    const int b = row >> 11;
    const int s = row & (SS - 1);
    const int half = lane >> 5;
    const int li = lane & 31;
    const int h = hp * 2 + half;
    const int d0 = li * 2;

    const unsigned short* base = qkv + (size_t)row * (3 * DD) + h * HDD + d0;
    const unsigned int qu = *(const unsigned int*)base;
    const unsigned int ku = *(const unsigned int*)(base + DD);
    const unsigned int vu = *(const unsigned int*)(base + 2 * DD);
    const float q0 = b2f((unsigned short)qu), q1 = b2f((unsigned short)(qu >> 16));
    const float k0 = b2f((unsigned short)ku), k1 = b2f((unsigned short)(ku >> 16));

    const float mq = half_sum32(q0 + q1) * (1.f / 64.f);
    const float dq0 = q0 - mq, dq1 = q1 - mq;
    const float varq = half_sum32(dq0 * dq0 + dq1 * dq1) * (1.f / 64.f);
    const float rsq = rsqrtf(varq + EPS);

    const float mk = half_sum32(k0 + k1) * (1.f / 64.f);
    const float dk0 = k0 - mk, dk1 = k1 - mk;
    const float vark = half_sum32(dk0 * dk0 + dk1 * dk1) * (1.f / 64.f);
    const float rsk = rsqrtf(vark + EPS);

    const float2 qs = *(const float2*)(q_scale + d0);
    const float2 ks = *(const float2*)(k_scale + d0);
    const float yq0 = dq0 * rsq * qs.x, yq1 = dq1 * rsq * qs.y;
    const float yk0 = dk0 * rsk * ks.x, yk1 = dk1 * rsk * ks.y;

    const int i0 = d0 & 31;
    const float2 cv = *(const float2*)(ctab + s * 32 + i0);
    const float2 sv = *(const float2*)(stab + s * 32 + i0);

    const float pq0 = __shfl_xor(yq0, 16), pq1 = __shfl_xor(yq1, 16);
    const float pk0 = __shfl_xor(yk0, 16), pk1 = __shfl_xor(yk1, 16);
    const bool lo = (li < 16);
    const float rq0 = lo ? -pq0 : pq0, rq1 = lo ? -pq1 : pq1;
    const float rk0 = lo ? -pk0 : pk0, rk1 = lo ? -pk1 : pk1;

    const float SC = 0.18033688011112042f;   // 0.125 * log2(e)
    const float oq0 = (yq0 * cv.x + rq0 * sv.x) * SC;
    const float oq1 = (yq1 * cv.y + rq1 * sv.y) * SC;
    const float ok0 = yk0 * cv.x + rk0 * sv.x;
    const float ok1 = yk1 * cv.y + rk1 * sv.y;

    const size_t oidx = (((size_t)(b * HH + h) * SS) + s) * HDD + d0;
    *(unsigned int*)(qt + oidx) = pack2bf(oq0, oq1);
    *(unsigned int*)(kt + oidx) = pack2bf(ok0, ok1);
    *(unsigned int*)(vt + oidx) = vu;
}

// ---------------------------------------------------------------------------
// Kernel 3b: V transpose  [bh][s][d] -> [bh][d][s]  (bf16)
// ---------------------------------------------------------------------------
__global__ __launch_bounds__(256) void transpose_v(const unsigned short* __restrict__ vt,
                                                   unsigned short* __restrict__ vtT) {
    __shared__ unsigned short tile[64][72];
    const int bh = blockIdx.x >> 5;
    const int s0 = (blockIdx.x & 31) * 64;
    const int t = threadIdx.x;
    const int row = t >> 2;
    const int c0 = (t & 3) * 16;
    const unsigned short* src = vt + ((size_t)bh * SS + s0 + row) * HDD + c0;
    *(uint4*)&tile[row][c0]     = *(const uint4*)(src);
    *(uint4*)&tile[row][c0 + 8] = *(const uint4*)(src + 8);
    __syncthreads();
    unsigned short outv[16];
#pragma unroll
    for (int i = 0; i < 16; i++) outv[i] = tile[c0 + i][row];
    unsigned short* dst = vtT + ((size_t)bh * HDD + row) * SS + s0 + c0;
    *(uint4*)dst       = *(uint4*)&outv[0];
    *(uint4*)(dst + 8) = *(uint4*)&outv[8];
}

// ---------------------------------------------------------------------------
// Kernel 4: MFMA flash attention (r7-proven): split-K x2, XOR-swizzled LDS,
// fixed max M=12, exp2 domain, l via ones-MFMA, LDS-staged K/V.
// ---------------------------------------------------------------------------
__global__ __launch_bounds__(256, 4) void attn_mfma(const unsigned short* __restrict__ qt,
                                                    const unsigned short* __restrict__ kt,
                                                    const unsigned short* __restrict__ vtT,
                                                    float* __restrict__ Opart,
                                                    float* __restrict__ lpart) {
    __shared__ __align__(16) unsigned short KsS[64 * 64];     // 8 KB [key][d]
    __shared__ __align__(16) unsigned short VsS[64 * 64];     // 8 KB [d][key]
    __shared__ __align__(16) unsigned short PbS[4][32 * 64];  // 16 KB [q][key]

    const int bh = blockIdx.x >> 4;
    const int q0 = (blockIdx.x & 15) * 128;
    const int ks = blockIdx.y;
    const int t = threadIdx.x;
    const int wq = t >> 6;
    const int lane = t & 63;
    const int m16 = lane & 15;
    const int quad = lane >> 4;
    const int m7 = m16 & 7;

    const int koff = m16 * 64 + (quad ^ m7) * 8;
    const int srow = t >> 2;
    const int sch = (t & 3) * 2;
    const int sw0 = srow * 64 + ((sch)     ^ (srow & 7)) * 8;
    const int sw1 = srow * 64 + ((sch + 1) ^ (srow & 7)) * 8;
    const int pwb = m16 * 64 + 4 * (quad & 1);
    const int qh = quad >> 1;

    bf16x8 qb[2][2];
#pragma unroll
    for (int u = 0; u < 2; u++) {
        const unsigned short* qp =
            qt + ((size_t)bh * SS + q0 + wq * 32 + u * 16 + m16) * HDD + quad * 8;
        qb[u][0] = *(const bf16x8*)qp;
        qb[u][1] = *(const bf16x8*)(qp + 32);
    }

    bf16x8 ones;
#pragma unroll
    for (int j = 0; j < 8; j++) ones[j] = (__bf16)1.0f;

    f32x4 O[2][4];
#pragma unroll
    for (int u = 0; u < 2; u++)
#pragma unroll
        for (int f = 0; f < 4; f++) O[u][f] = (f32x4){0.f, 0.f, 0.f, 0.f};
    f32x4 lacc[2] = {(f32x4){0.f, 0.f, 0.f, 0.f}, (f32x4){0.f, 0.f, 0.f, 0.f}};

    const unsigned short* kbase = kt + (size_t)bh * SS * HDD;
    const unsigned short* vbase = vtT + (size_t)bh * HDD * SS;
    const f32x4 cinit = (f32x4){-12.f, -12.f, -12.f, -12.f};

    const int kstart = ks * (SS / 2);
    for (int k0 = kstart; k0 < kstart + SS / 2; k0 += 64) {
        __syncthreads();
        {
            const unsigned short* ksrc = kbase + (size_t)(k0 + srow) * HDD + sch * 8;
            *(uint4*)&KsS[sw0] = *(const uint4*)ksrc;
            *(uint4*)&KsS[sw1] = *(const uint4*)(ksrc + 8);
            const unsigned short* vsrc = vbase + (size_t)srow * SS + k0 + sch * 8;
            *(uint4*)&VsS[sw0] = *(const uint4*)vsrc;
            *(uint4*)&VsS[sw1] = *(const uint4*)(vsrc + 8);
        }
        __syncthreads();

        f32x4 S[2][4];
#pragma unroll
        for (int g = 0; g < 4; g++) {
            const bf16x8 ka0 = *(const bf16x8*)&KsS[g * 1024 + koff];
            const bf16x8 ka1 = *(const bf16x8*)&KsS[g * 1024 + (koff ^ 32)];
#pragma unroll
            for (int u = 0; u < 2; u++) {
                f32x4 a = __builtin_amdgcn_mfma_f32_16x16x32_bf16(ka0, qb[u][0], cinit, 0, 0, 0);
                a = __builtin_amdgcn_mfma_f32_16x16x32_bf16(ka1, qb[u][1], a, 0, 0, 0);
                S[u][g] = a;
            }
        }

#pragma unroll
        for (int u = 0; u < 2; u++) {
#pragma unroll
            for (int g = 0; g < 4; g++) {
                const float p0 = exp2f(S[u][g][0]);
                const float p1 = exp2f(S[u][g][1]);
                const float p2 = exp2f(S[u][g][2]);
                const float p3 = exp2f(S[u][g][3]);
                *(uint2*)&PbS[wq][u * 1024 + pwb + ((2 * g + qh) ^ m7) * 8] =
                    pack4bf(p0, p1, p2, p3);
            }
        }
        asm volatile("s_waitcnt lgkmcnt(0)" ::: "memory");

        bf16x8 pb[2][2];
#pragma unroll
        for (int u = 0; u < 2; u++) {
            pb[u][0] = *(const bf16x8*)&PbS[wq][u * 1024 + koff];
            pb[u][1] = *(const bf16x8*)&PbS[wq][u * 1024 + (koff ^ 32)];
        }

#pragma unroll
        for (int u = 0; u < 2; u++) {
            lacc[u] = __builtin_amdgcn_mfma_f32_16x16x32_bf16(ones, pb[u][0], lacc[u], 0, 0, 0);
            lacc[u] = __builtin_amdgcn_mfma_f32_16x16x32_bf16(ones, pb[u][1], lacc[u], 0, 0, 0);
        }
#pragma unroll
        for (int f = 0; f < 4; f++) {
            const bf16x8 va0 = *(const bf16x8*)&VsS[f * 1024 + koff];
            const bf16x8 va1 = *(const bf16x8*)&VsS[f * 1024 + (koff ^ 32)];
#pragma unroll
            for (int u = 0; u < 2; u++) {
                O[u][f] = __builtin_amdgcn_mfma_f32_16x16x32_bf16(va0, pb[u][0], O[u][f], 0, 0, 0);
                O[u][f] = __builtin_amdgcn_mfma_f32_16x16x32_bf16(va1, pb[u][1], O[u][f], 0, 0, 0);
            }
        }
    }

    const int b_ = bh >> 4;
    const int h_ = bh & 15;
    float* obase0 = Opart + (size_t)ks * ((size_t)BB * SS * DD);
#pragma unroll
    for (int u = 0; u < 2; u++) {
        const int s_ = q0 + wq * 32 + u * 16 + m16;
        float* orow = obase0 + ((size_t)b_ * SS + s_) * DD + h_ * HDD;
#pragma unroll
        for (int f = 0; f < 4; f++)
            *(f32x4*)(orow + f * 16 + quad * 4) = O[u][f];
        if (quad == 0)
            lpart[ks * (32 * SS) + bh * SS + s_] = lacc[u][0];
    }
}

// ---------------------------------------------------------------------------
// Kernel 4b: combine split-K partials -> bf16 attn [b][s][h*64+d]
// ---------------------------------------------------------------------------
__global__ __launch_bounds__(256) void combine_attn(const float* __restrict__ Opart,
                                                    const float* __restrict__ lpart,
                                                    unsigned short* __restrict__ attn) {
    const int row = blockIdx.x;            // 0..4095 = b*S+s
    const int t = threadIdx.x;
    const int c = t * 4;
    const int h = t >> 4;
    const int b = row >> 11;
    const int s = row & (SS - 1);

    const size_t off = (size_t)row * DD + c;
    const float4 o0 = *(const float4*)(Opart + off);
    const float4 o1 = *(const float4*)(Opart + (size_t)BB * SS * DD + off);
    const int li = (b * HH + h) * SS + s;
    const float inv = 1.f / (lpart[li] + lpart[32 * SS + li]);

    *(uint2*)(attn + off) = pack4bf((o0.x + o1.x) * inv, (o0.y + o1.y) * inv,
                                    (o0.z + o1.z) * inv, (o0.w + o1.w) * inv);
}

// ---------------------------------------------------------------------------
// launch
// ---------------------------------------------------------------------------
extern "C" void kernel_launch(void* const* d_in, const int* in_sizes, int n_in,
                              void* d_out, int out_size, void* d_ws, size_t ws_size,
                              hipStream_t stream) {
    const float* x        = (const float*)d_in[0];
    const float* w_qkv    = (const float*)d_in[1];
    const float* b_qkv    = (const float*)d_in[2];
    const float* w_out    = (const float*)d_in[3];
    const float* b_out    = (const float*)d_in[4];
    const float* ln_scale = (const float*)d_in[5];
    const float* ln_bias  = (const float*)d_in[6];
    const float* q_scale  = (const float*)d_in[7];
    const float* k_scale  = (const float*)d_in[8];
    float* out = (float*)d_out;

    char* ws = (char*)d_ws;
    const size_t MB = 1024 * 1024;
    // layout:
    //   [0,8)    xn (bf16)
    //   [8,8.5)  lpart   [9,9.25) ctab   [10,10.25) stab
    //   [16,40)  qkv (bf16) — consumed by head_ln_rope, then
    //   [16,48)  Opart (fp32, 2 splits) reuses it
    //   [64,70)  wqkvT  [70,72) woutT  [72,80) qt  [80,88) kt
    //   [88,96)  vt     [96,104) vtT   [104,112) attn
    unsigned short* xn    = (unsigned short*)(ws + 0);
    float*          lpart = (float*)(ws + 8 * MB);
    float*          ctab  = (float*)(ws + 9 * MB);
    float*          stab  = (float*)(ws + 10 * MB);
    unsigned short* qkv   = (unsigned short*)(ws + 16 * MB);
    float*          Opart = (float*)(ws + 16 * MB);
    unsigned short* wqkvT = (unsigned short*)(ws + 64 * MB);
    unsigned short* woutT = (unsigned short*)(ws + 70 * MB);
    unsigned short* qt    = (unsigned short*)(ws + 72 * MB);
    unsigned short* kt    = (unsigned short*)(ws + 80 * MB);
    unsigned short* vt    = (unsigned short*)(ws + 88 * MB);
    unsigned short* vtT   = (unsigned short*)(ws + 96 * MB);
    unsigned short* attn  = (unsigned short*)(ws + 104 * MB);

    const int M = BB * SS;   // 4096

    cast_transpose<<<dim3(3 * DD / 32, DD / 32), 256, 0, stream>>>(w_qkv, wqkvT, DD, 3 * DD);
    cast_transpose<<<dim3(DD / 32, DD / 32), 256, 0, stream>>>(w_out, woutT, DD, DD);
    rope_tables<<<SS * 32 / 256, 256, 0, stream>>>(ctab, stab);

    ln_kernel<<<M, 256, 0, stream>>>(x, ln_scale, ln_bias, xn);

    gemm_mfma_bt_bf16<<<dim3(3 * DD / 128, M / 128), 256, 0, stream>>>(xn, wqkvT, b_qkv,
                                                                       qkv, M, 3 * DD, DD);

    head_ln_rope<<<M * HH / 8, 256, 0, stream>>>(qkv, q_scale, k_scale, ctab, stab,
                                                 qt, kt, vt);

    transpose_v<<<BB * HH * (SS / 64), 256, 0, stream>>>(vt, vtT);

    attn_mfma<<<dim3(BB * HH * (SS / 128), 2), 256, 0, stream>>>(qt, kt, vtT, Opart, lpart);

    combine_attn<<<M, 256, 0, stream>>>(Opart, lpart, attn);

    gemm_mfma_bt<<<dim3(DD / 128, M / 128), 256, 0, stream>>>(attn, woutT, b_out, out,
                                                              M, DD, DD);
}